// Round 1
// baseline (154.783 us; speedup 1.0000x reference)
//
#include <hip/hip_runtime.h>

// MultiScaleSampler R8: inverse-map restructure.
// Old: fill_zero(25MB) + per-point kernel scattering 12B to out[yi*3]
//      -> 63.6MB of unmerged random 32B-sector writes = the bottleneck.
// New: (1) memset ws sentinel; (2) scatter_feat packs (f16 fx, f16 fy)
//      into u32 feats[pixel] (4B random writes to an 8.4MB region);
//      (3) dense MLP kernel walks pixels, reads feats coalesced, writes
//      out fully coalesced (25.2MB exact), zeros where sentinel.
//      fill_zero eliminated; dsda recomputed from the slot index (yi==pixel).
// MLP core (fragments, wave-private LDS layout, LAYER macro, layer-4 stash,
// softmax) is verbatim from the harness-verified R7 kernel.

#define W_IMG 2048
#define NF    32

typedef __attribute__((ext_vector_type(8))) _Float16 f16x8;
typedef __attribute__((ext_vector_type(4))) _Float16 f16x4;
typedef __attribute__((ext_vector_type(4))) float    f32x4;
typedef __attribute__((ext_vector_type(4))) float    fvec4;
typedef __attribute__((ext_vector_type(4))) int      ivec4;

static __device__ __forceinline__ unsigned packfeat(float fx, float fy) {
    unsigned short ux = __builtin_bit_cast(unsigned short, (_Float16)fx);
    unsigned short uy = __builtin_bit_cast(unsigned short, (_Float16)fy);
    return ((unsigned)uy << 16) | (unsigned)ux;
}

// K1: scatter packed fractional coords into feats[pixel].
// Valid packs never equal 0xFFFFFFFF (fy in [0,1) -> high half < 0x3C00).
__global__ __launch_bounds__(256) void scatter_feat(
    const float* __restrict__ grid, const int* __restrict__ yi,
    unsigned* __restrict__ feats, int N)
{
    int t = blockIdx.x * blockDim.x + threadIdx.x;
    int stride = gridDim.x * blockDim.x;
    if ((N & 3) == 0) {
        int n4 = N >> 2;
        const fvec4* gx4 = (const fvec4*)grid;
        const fvec4* gy4 = (const fvec4*)(grid + N);
        const ivec4* yi4 = (const ivec4*)yi;
        for (int j = t; j < n4; j += stride) {
            fvec4 x = __builtin_nontemporal_load((fvec4*)(gx4 + j));
            fvec4 y = __builtin_nontemporal_load((fvec4*)(gy4 + j));
            ivec4 p = __builtin_nontemporal_load((ivec4*)(yi4 + j));
#pragma unroll
            for (int k = 0; k < 4; ++k) {
                float fx = x[k] - floorf(x[k]);
                float fy = y[k] - floorf(y[k]);
                feats[p[k]] = packfeat(fx, fy);   // plain store: want L2 merge
            }
        }
    } else {
        for (int i = t; i < N; i += stride) {
            float gx = grid[i], gy = grid[N + i];
            feats[yi[i]] = packfeat(gx - floorf(gx), gy - floorf(gy));
        }
    }
}

// K2: dense per-pixel MLP. 512 pixels/block (4 waves x 128), wave-private LDS.
__global__ __launch_bounds__(256, 4) void msampler_mlp(
    const unsigned* __restrict__ feats,   // (H*W,) packed or sentinel
    const float* __restrict__ m,          // (3,3)
    const float* __restrict__ W1, const float* __restrict__ b1,   // (5,32),(32)
    const float* __restrict__ W2, const float* __restrict__ b2,   // (32,32),(32)
    const float* __restrict__ W3, const float* __restrict__ b3,   // (32,32),(32)
    const float* __restrict__ W4, const float* __restrict__ b4,   // (32,3),(3)
    float* __restrict__ out, int HW)
{
    const int tid  = threadIdx.x;
    const int lane = tid & 63;
    const int wave = tid >> 6;
    const int lm   = lane & 15;
    const int lq   = lane >> 4;

    __shared__ __align__(16) char smem[4 * 8192];
    char* buf = smem + wave * 8192;   // 8 tiles x 1024B, wave-private

    // ---- one-time weight fragments (A = W^T: A[m=out][k=in]) ----
    f16x8 a1[2], a2[2], a3[2], a4;
    f32x4 cb1[2], cb2[2], cb3[2], cb4;
#pragma unroll
    for (int mh = 0; mh < 2; ++mh) {
        int outc = 16 * mh + lm;
#pragma unroll
        for (int j = 0; j < 8; ++j) {
            int k = lq * 8 + j;
            a1[mh][j] = (k < 5) ? (_Float16)W1[k * NF + outc] : (_Float16)0.0f;
            a2[mh][j] = (_Float16)W2[k * NF + outc];
            a3[mh][j] = (_Float16)W3[k * NF + outc];
        }
#pragma unroll
        for (int r = 0; r < 4; ++r) {
            int o = 16 * mh + lq * 4 + r;
            cb1[mh][r] = b1[o];
            cb2[mh][r] = b2[o];
            cb3[mh][r] = b3[o];
        }
    }
#pragma unroll
    for (int j = 0; j < 8; ++j) {
        int k = lq * 8 + j;
        a4[j] = (lm < 3) ? (_Float16)W4[k * 3 + lm] : (_Float16)0.0f;
    }
#pragma unroll
    for (int r = 0; r < 4; ++r) {
        int o = lq * 4 + r;
        cb4[r] = (o < 3) ? b4[o] : 0.f;
    }

    // ---- uniform homography scalars ----
    float m00=m[0], m01=m[1], m02=m[2];
    float m10=m[3], m11=m[4], m12=m[5];
    float m20=m[6], m21=m[7], m22=m[8];
    float det = m00*(m11*m22 - m12*m21)
              - m01*(m10*m22 - m12*m20)
              + m02*(m10*m21 - m11*m20);
    float adet = fabsf(det);

    // ---- features for 2 pixels/lane from packed feats; write B-frag slot ----
    const int i0 = blockIdx.x * 512 + wave * 128;
    unsigned fwv[2];
#pragma unroll
    for (int t = 0; t < 2; ++t) {
        int s  = i0 + t * 64 + lane;
        int sc = s < HW ? s : HW - 1;
        unsigned w = feats[sc];
        fwv[t] = w;
        int py = sc >> 11;            // / 2048
        int px = sc & (W_IMG - 1);    // % 2048
        float denom = m20*(float)px + m21*(float)py + m22;
        float ad    = fabsf(denom);
        float dsda  = fminf(adet / (ad*ad*ad), 60000.f);  // f16-range clamp
        _Float16 hx = __builtin_bit_cast(_Float16, (unsigned short)(w & 0xFFFFu));
        _Float16 hy = __builtin_bit_cast(_Float16, (unsigned short)(w >> 16));
        float fxf = (float)hx, fyf = (float)hy;
        f16x8 f;
        f[0] = hx;                   f[1] = hy;
        f[2] = (_Float16)(1.f-fxf);  f[3] = (_Float16)(1.f-fyf);
        f[4] = (_Float16)dsda;       f[5] = (_Float16)0.0f;
        f[6] = (_Float16)0.0f;       f[7] = (_Float16)0.0f;
        int g = t * 4 + lq;          // tile of this pixel
        *(f16x8*)(buf + g * 1024 + lm * 16) = f;   // consumer slot (lq_c=0, lm)
    }
    // zero k=8..31 regions of all 8 tiles (48 chunks x 16B per tile)
    {
        f16x8 z = {};
#pragma unroll
        for (int j = 0; j < 6; ++j) {
            int T  = lane >> 3;
            int ch = (lane & 7) + 8 * j;
            *(f16x8*)(buf + T * 1024 + 256 + ch * 16) = z;
        }
    }

    // write offset for D-frag (mh, tile T): consumer lane (2mh + lq/2, lm),
    // half (lq&1)
    const int woff = ((lq >> 1) * 16 + lm) * 16 + (lq & 1) * 8;

    // ---- layers 1..3: read B-frags, MFMA, relu+clamp+cvt, write frags ----
#define LAYER(AF, CB)                                                          \
    _Pragma("unroll")                                                          \
    for (int tg = 0; tg < 2; ++tg) {                                           \
        f16x8 bf[4];                                                           \
        _Pragma("unroll")                                                      \
        for (int q = 0; q < 4; ++q)                                            \
            bf[q] = *(const f16x8*)(buf + (tg*4 + q) * 1024 + lane * 16);      \
        _Pragma("unroll")                                                      \
        for (int q = 0; q < 4; ++q) {                                          \
            int T = tg * 4 + q;                                                \
            _Pragma("unroll")                                                  \
            for (int mh = 0; mh < 2; ++mh) {                                   \
                f32x4 d = __builtin_amdgcn_mfma_f32_16x16x32_f16(              \
                    AF[mh], bf[q], CB[mh], 0, 0, 0);                           \
                f16x4 o;                                                       \
                _Pragma("unroll")                                              \
                for (int r = 0; r < 4; ++r)                                    \
                    o[r] = (_Float16)fminf(fmaxf(d[r], 0.f), 60000.f);         \
                *(f16x4*)(buf + T * 1024 + mh * 512 + woff) = o;               \
            }                                                                  \
        }                                                                      \
    }

    LAYER(a1, cb1)
    LAYER(a2, cb2)
    LAYER(a3, cb3)
#undef LAYER

    // ---- layer 4: one MFMA per tile; logits (rows 0..2) sit in lq==0 lanes;
    //      stash to pixel-indexed slots (first 2KB, tiles already consumed) ----
#pragma unroll
    for (int tg = 0; tg < 2; ++tg) {
        f16x8 bf[4];
#pragma unroll
        for (int q = 0; q < 4; ++q)
            bf[q] = *(const f16x8*)(buf + (tg*4 + q) * 1024 + lane * 16);
#pragma unroll
        for (int q = 0; q < 4; ++q) {
            int T = tg * 4 + q;
            f32x4 d = __builtin_amdgcn_mfma_f32_16x16x32_f16(a4, bf[q], cb4, 0, 0, 0);
            if (lq == 0)
                *(f32x4*)(buf + (T * 16 + lm) * 16) = d;   // slot, 16B
        }
    }

    // ---- softmax + dense coalesced write (zeros where sentinel) ----
#pragma unroll
    for (int t = 0; t < 2; ++t) {
        int s = t * 64 + lane;
        f32x4 L = *(const f32x4*)(buf + s * 16);
        float l0 = L[0], l1 = L[1], l2 = L[2];
        float mx = fmaxf(l0, fmaxf(l1, l2));
        float e0 = __expf(l0 - mx), e1 = __expf(l1 - mx), e2 = __expf(l2 - mx);
        float inv = 1.f / (e0 + e1 + e2);
        int gslot = i0 + s;
        if (gslot < HW) {
            bool v = (fwv[t] != 0xFFFFFFFFu);
            float o0 = v ? e0 * inv : 0.f;
            float o1 = v ? e1 * inv : 0.f;
            float o2 = v ? e2 * inv : 0.f;
            int o = gslot * 3;
            out[o + 0] = o0;
            out[o + 1] = o1;
            out[o + 2] = o2;
        }
    }
}

extern "C" void kernel_launch(void* const* d_in, const int* in_sizes, int n_in,
                              void* d_out, int out_size, void* d_ws, size_t ws_size,
                              hipStream_t stream) {
    const float* grid = (const float*)d_in[0];
    const int*   yi   = (const int*)  d_in[1];
    const float* m    = (const float*)d_in[2];
    const float* W1   = (const float*)d_in[3];
    const float* b1   = (const float*)d_in[4];
    const float* W2   = (const float*)d_in[5];
    const float* b2   = (const float*)d_in[6];
    const float* W3   = (const float*)d_in[7];
    const float* b3   = (const float*)d_in[8];
    const float* W4   = (const float*)d_in[9];
    const float* b4   = (const float*)d_in[10];
    float* out = (float*)d_out;

    int N  = in_sizes[1];      // number of sampled points
    int HW = out_size / 3;     // number of output pixels

    unsigned* feats = (unsigned*)d_ws;

    // sentinel init: 0xFFFFFFFF can never be a valid pack (fy in [0,1))
    hipMemsetAsync(feats, 0xFF, (size_t)HW * sizeof(unsigned), stream);

    int sblocks = ((N >> 2) + 255) / 256;
    if (sblocks < 1) sblocks = 1;
    if (sblocks > 4096) sblocks = 4096;
    scatter_feat<<<sblocks, 256, 0, stream>>>(grid, yi, feats, N);

    int blocks = (HW + 511) / 512;   // 512 pixels per block (4 waves x 128)
    msampler_mlp<<<blocks, 256, 0, stream>>>(
        feats, m, W1, b1, W2, b2, W3, b3, W4, b4, out, HW);
}